// Round 12
// baseline (277.910 us; speedup 1.0000x reference)
//
#include <hip/hip_runtime.h>
#include <hip/hip_bf16.h>

// B=64, I=64, O=64, G=4096, X=4, RHO=1
#define BB 64
#define II 64
#define OO 64
#define GG 4096
#define KP 64            // g per phase
#define NOC 8            // o-chunks -> grid 64 x 8 = 512 blocks
#define NPH (GG / KP)    // 64 phases

typedef short bf16x8 __attribute__((ext_vector_type(8)));
typedef short bf16x4 __attribute__((ext_vector_type(4)));
typedef float f32x4  __attribute__((ext_vector_type(4)));

static __device__ __forceinline__ short f2bf(float f) {
    __hip_bfloat16 h = __float2bfloat16(f);
    return __builtin_bit_cast(short, h);
}

// Barrier with LDS-only drain: global loads stay in flight across it.
static __device__ __forceinline__ void lds_barrier() {
    asm volatile("s_waitcnt lgkmcnt(0)" ::: "memory");
    __builtin_amdgcn_s_barrier();
}

// ---------------------------------------------------------------------------
// r12: N-SPLIT restructure. Block (i, oc) owns C[64 b][8 o][4 x] and walks
// ALL 4096 g  ->  reduction is over i only: partials 32 MB -> 4 MB (saves
// ~56 MB of HBM round-trip vs r11's split-K), weights read once as 8
// contiguous 64-KB o-row streams. rbf recomputed 8x (fits VALU budget:
// ~960 cyc/SIMD/phase vs 1560-cyc HBM phase budget).
//
// Per phase (KP=64): wave wv stages o-row oc*8+wv (1 float4/lane = 1 KB
// contiguous/inst), converts to bf16 into Bs[32 n][64 k]; rbf -> As[64 b]
// [64 k]; one lds_barrier; 2 k-steps x 1 MFMA/wave (wave -> tile (mt,nt) =
// (wv>>1, wv&1)). Depth-2 reg prefetch (preA/preB, static 2-phase unroll)
// + sched_barrier(0) after reissue pins the load issue point (r8's sink
// countermeasure). Phase rotation s=(i+8*oc)&63 decorrelates addr bits
// 10-15 (r10's confirmed win).
//
// Swizzle algebra (both tiles, rows of 64 bf16 = 128 B, XOR in 8-bf16
// units): elem (row, k) at row*64 + (k ^ ((row&7)<<3)).
//   Bs write: n = wv*4+x uniform/wave, col = lane^c -> 2 lanes/bank, free.
//   As write: bf16x4 at kb ^ ((brow&7)<<3), kb 4-aligned, XOR bits 3-5 ok.
//   b128 reads: unit' = (kk*4+lg) ^ (row&7) -> uniform 8 lanes/unit =
//   wave64-b128 minimum, conflict-free. Read inverse: stored g at
//   g^c == k^c  <=> g == k. Verified.
// ---------------------------------------------------------------------------
__global__ __launch_bounds__(512, 4)
void kan_main(const float* __restrict__ xg, const float* __restrict__ grd,
              const float* __restrict__ wts, float* __restrict__ dst,
              int atomic_mode)
{
    __shared__ __align__(16) unsigned short Bs[2][32 * KP];  // 4KB x2
    __shared__ __align__(16) unsigned short As[2][BB * KP];  // 8KB x2

    const int i  = blockIdx.x;
    const int oc = blockIdx.y;
    const int s  = (i + oc * 8) & (NPH - 1);   // phase rotation

    const int t    = threadIdx.x;
    const int lane = t & 63;
    const int wv   = t >> 6;

    // weight staging: wave wv stages o-row oc*8+wv; lane = g within phase
    const float4* wbase = reinterpret_cast<const float4*>(wts)
        + ((size_t)i * OO + oc * 8 + wv) * GG + lane;

    // rbf map: thread computes 8 g for one b-row
    const int brow = t >> 3;
    const int oct  = t & 7;
    const float4* gp4 = reinterpret_cast<const float4*>(grd);
    const float4  xv  = reinterpret_cast<const float4*>(xg)[brow * II + i];

    const int mt = wv >> 1, nt = wv & 1;     // wave's output tile
    const int lg = lane >> 4, r16 = lane & 15;

    f32x4 acc = {0.f, 0.f, 0.f, 0.f};

    // depth-2 prologue
    float4 preA = wbase[(size_t)(s) * KP];
    float4 preB = wbase[(size_t)((s + 1) & (NPH - 1)) * KP];
    __builtin_amdgcn_sched_barrier(0);

    for (int pp = 0; pp < NPH; pp += 2) {
        // ================= even phase: buf 0, preA ========================
        {
            const int cp = (pp + s) & (NPH - 1);
            float4 gv[8];
            #pragma unroll
            for (int e = 0; e < 8; ++e) gv[e] = gp4[cp * KP + oct * 8 + e];

            {   // consume weights -> Bs[0]
                const float wf[4] = {preA.x, preA.y, preA.z, preA.w};
                #pragma unroll
                for (int x = 0; x < 4; ++x) {
                    const int n = wv * 4 + x;
                    Bs[0][n * KP + (lane ^ ((n & 7) << 3))] =
                        (unsigned short)f2bf(wf[x]);
                }
            }
            if (pp + 2 < NPH)
                preA = wbase[(size_t)((pp + 2 + s) & (NPH - 1)) * KP];
            __builtin_amdgcn_sched_barrier(0);

            #pragma unroll
            for (int h = 0; h < 2; ++h) {    // rbf -> As[0]
                bf16x4 av;
                #pragma unroll
                for (int e = 0; e < 4; ++e) {
                    const float4 g = gv[h * 4 + e];
                    const float d0 = xv.x - g.x, d1 = xv.y - g.y,
                                d2 = xv.z - g.z, d3 = xv.w - g.w;
                    av[e] = f2bf(__expf(-(d0*d0 + d1*d1 + d2*d2 + d3*d3)));
                }
                const int kb = oct * 8 + h * 4;
                *reinterpret_cast<bf16x4*>(
                    &As[0][brow * KP + (kb ^ ((brow & 7) << 3))]) = av;
            }

            lds_barrier();

            #pragma unroll
            for (int kk = 0; kk < 2; ++kk) {
                const int kb = kk * 32 + lg * 8;
                const int rA = mt * 16 + r16;
                const int rB = nt * 16 + r16;
                bf16x8 af = *reinterpret_cast<const bf16x8*>(
                    &As[0][rA * KP + (kb ^ ((rA & 7) << 3))]);
                bf16x8 bf = *reinterpret_cast<const bf16x8*>(
                    &Bs[0][rB * KP + (kb ^ ((rB & 7) << 3))]);
                acc = __builtin_amdgcn_mfma_f32_16x16x32_bf16(af, bf, acc,
                                                              0, 0, 0);
            }
            // single barrier per phase: next phase writes buf 1; buf 0 is
            // next overwritten at pp+2, after barrier pp+1 drains all reads.
        }
        // ================= odd phase: buf 1, preB =========================
        {
            const int cp = (pp + 1 + s) & (NPH - 1);
            float4 gv[8];
            #pragma unroll
            for (int e = 0; e < 8; ++e) gv[e] = gp4[cp * KP + oct * 8 + e];

            {
                const float wf[4] = {preB.x, preB.y, preB.z, preB.w};
                #pragma unroll
                for (int x = 0; x < 4; ++x) {
                    const int n = wv * 4 + x;
                    Bs[1][n * KP + (lane ^ ((n & 7) << 3))] =
                        (unsigned short)f2bf(wf[x]);
                }
            }
            if (pp + 3 < NPH)
                preB = wbase[(size_t)((pp + 3 + s) & (NPH - 1)) * KP];
            __builtin_amdgcn_sched_barrier(0);

            #pragma unroll
            for (int h = 0; h < 2; ++h) {
                bf16x4 av;
                #pragma unroll
                for (int e = 0; e < 4; ++e) {
                    const float4 g = gv[h * 4 + e];
                    const float d0 = xv.x - g.x, d1 = xv.y - g.y,
                                d2 = xv.z - g.z, d3 = xv.w - g.w;
                    av[e] = f2bf(__expf(-(d0*d0 + d1*d1 + d2*d2 + d3*d3)));
                }
                const int kb = oct * 8 + h * 4;
                *reinterpret_cast<bf16x4*>(
                    &As[1][brow * KP + (kb ^ ((brow & 7) << 3))]) = av;
            }

            lds_barrier();

            #pragma unroll
            for (int kk = 0; kk < 2; ++kk) {
                const int kb = kk * 32 + lg * 8;
                const int rA = mt * 16 + r16;
                const int rB = nt * 16 + r16;
                bf16x8 af = *reinterpret_cast<const bf16x8*>(
                    &As[1][rA * KP + (kb ^ ((rA & 7) << 3))]);
                bf16x8 bf = *reinterpret_cast<const bf16x8*>(
                    &Bs[1][rB * KP + (kb ^ ((rB & 7) << 3))]);
                acc = __builtin_amdgcn_mfma_f32_16x16x32_bf16(af, bf, acc,
                                                              0, 0, 0);
            }
        }
    }

    // ---- epilogue: C/D col=lane&15 -> n, row=(lane>>4)*4+reg -> m ----
    const int n  = oc * 32 + nt * 16 + r16;
    const int mb = mt * 16 + (lane >> 4) * 4;
    if (!atomic_mode) {
        float* pp_ = dst + (size_t)i * 16384;
        #pragma unroll
        for (int r = 0; r < 4; ++r)
            pp_[(mb + r) * 256 + n] = acc[r];
    } else {
        #pragma unroll
        for (int r = 0; r < 4; ++r)
            atomicAdd(&dst[(mb + r) * 256 + n], acc[r]);
    }
}

// ---------------------------------------------------------------------------
// Tail: sum 64 i-slices (4 MB) + SiLU/Cayley (Cl(2,0), static signs) + bias
// ---------------------------------------------------------------------------
__global__ __launch_bounds__(256)
void kan_tail(const float* __restrict__ part,
              const float* __restrict__ xg,
              const float* __restrict__ sw,
              const float* __restrict__ sb,
              float* __restrict__ out)
{
    const int j = blockIdx.x * 256 + threadIdx.x;    // (b,o) in [0,4096)
    const int b = j >> 6, o = j & 63;

    const float4* p4 = reinterpret_cast<const float4*>(part);
    float o0 = 0.f, o1 = 0.f, o2 = 0.f, o3 = 0.f;
    #pragma unroll 8
    for (int ii = 0; ii < 64; ++ii) {
        const float4 v = p4[(size_t)ii * 4096 + j];
        o0 += v.x; o1 += v.y; o2 += v.z; o3 += v.w;
    }

    const float4* xg4 = reinterpret_cast<const float4*>(xg);
    const float4* sw4 = reinterpret_cast<const float4*>(sw);
    const float4* sb4 = reinterpret_cast<const float4*>(sb);
    #pragma unroll 4
    for (int i = 0; i < II; ++i) {
        const float4 xvv = xg4[b * II + i];
        const float4 swv = sw4[i * OO + o];
        const float4 sbv = sb4[i * OO + o];
        const float s0 = xvv.x / (1.f + __expf(-xvv.x));
        const float s1 = xvv.y / (1.f + __expf(-xvv.y));
        const float s2 = xvv.z / (1.f + __expf(-xvv.z));
        const float s3 = xvv.w / (1.f + __expf(-xvv.w));
        o0 += swv.x * s0 + swv.y * s1 + swv.z * s2 - swv.w * s3 + sbv.x;
        o1 += swv.x * s1 + swv.y * s0 - swv.z * s3 + swv.w * s2 + sbv.y;
        o2 += swv.x * s2 + swv.y * s3 + swv.z * s0 - swv.w * s1 + sbv.z;
        o3 += swv.x * s3 + swv.y * s2 - swv.z * s1 + swv.w * s0 + sbv.w;
    }
    reinterpret_cast<float4*>(out)[j] = make_float4(o0, o1, o2, o3);
}

// ---------------------------------------------------------------------------
// Fallback-only final kernel (atomic path): main sums already in out
// ---------------------------------------------------------------------------
__global__ void kan_out(const float* __restrict__ xg,
                        const float* __restrict__ sw,
                        const float* __restrict__ sb,
                        float* __restrict__ out)
{
    const int t = blockIdx.x * 256 + threadIdx.x;    // (b,o)
    const int b = t >> 6, o = t & 63;

    const float4 v = reinterpret_cast<const float4*>(out)[t];
    float o0 = v.x, o1 = v.y, o2 = v.z, o3 = v.w;

    const float4* xg4 = reinterpret_cast<const float4*>(xg);
    const float4* sw4 = reinterpret_cast<const float4*>(sw);
    const float4* sb4 = reinterpret_cast<const float4*>(sb);
    #pragma unroll 4
    for (int i = 0; i < II; ++i) {
        const float4 xvv = xg4[b * II + i];
        const float4 swv = sw4[i * OO + o];
        const float4 sbv = sb4[i * OO + o];
        const float s0 = xvv.x / (1.f + __expf(-xvv.x));
        const float s1 = xvv.y / (1.f + __expf(-xvv.y));
        const float s2 = xvv.z / (1.f + __expf(-xvv.z));
        const float s3 = xvv.w / (1.f + __expf(-xvv.w));
        o0 += swv.x * s0 + swv.y * s1 + swv.z * s2 - swv.w * s3 + sbv.x;
        o1 += swv.x * s1 + swv.y * s0 - swv.z * s3 + swv.w * s2 + sbv.y;
        o2 += swv.x * s2 + swv.y * s3 + swv.z * s0 - swv.w * s1 + sbv.z;
        o3 += swv.x * s3 + swv.y * s2 - swv.z * s1 + swv.w * s0 + sbv.w;
    }
    reinterpret_cast<float4*>(out)[t] = make_float4(o0, o1, o2, o3);
}

// ---------------------------------------------------------------------------
extern "C" void kernel_launch(void* const* d_in, const int* in_sizes, int n_in,
                              void* d_out, int out_size, void* d_ws, size_t ws_size,
                              hipStream_t stream)
{
    const float* x   = (const float*)d_in[0];
    const float* grd = (const float*)d_in[1];
    const float* w   = (const float*)d_in[2];
    const float* sw  = (const float*)d_in[3];
    const float* sb  = (const float*)d_in[4];
    float* out = (float*)d_out;
    float* ws  = (float*)d_ws;

    const size_t need = (size_t)64 * 16384 * 4;   // 64 i-slices = 4 MB

    if (ws_size >= need) {
        kan_main<<<dim3(64, NOC), 512, 0, stream>>>(x, grd, w, ws, 0);
        kan_tail<<<16, 256, 0, stream>>>(ws, x, sw, sb, out);
    } else {
        hipMemsetAsync(d_out, 0, (size_t)out_size * sizeof(float), stream);
        kan_main<<<dim3(64, NOC), 512, 0, stream>>>(x, grd, w, out, 1);
        kan_out<<<16, 256, 0, stream>>>(x, sw, sb, out);
    }
}

// Round 13
// 92.558 us; speedup vs baseline: 3.0026x; 3.0026x over previous
//
#include <hip/hip_runtime.h>
#include <hip/hip_bf16.h>

// B=64, I=64, O=64, G=4096, X=4, RHO=1
#define BB 64
#define II 64
#define OO 64
#define GG 4096
#define KP 32            // g per phase
#define NCH 4            // split-K chunks -> grid 64 x 4 = 256 blocks
#define GC (GG / NCH)    // 1024 g per block
#define NPH (GC / KP)    // 32 phases
#define NSL (II * NCH)   // 256 partial slices (bf16)

typedef short bf16x8 __attribute__((ext_vector_type(8)));
typedef short bf16x2 __attribute__((ext_vector_type(2)));
typedef float f32x4  __attribute__((ext_vector_type(4)));
typedef unsigned short u16x4 __attribute__((ext_vector_type(4)));

static __device__ __forceinline__ unsigned short f2bfu(float f) {
    __hip_bfloat16 h = __float2bfloat16(f);
    return __builtin_bit_cast(unsigned short, h);
}
static __device__ __forceinline__ float bfu2f(unsigned short u) {
    unsigned int v = (unsigned int)u << 16;
    return __builtin_bit_cast(float, v);
}

// ---------------------------------------------------------------------------
// r13 = r11 structure (the proven one) with the partial round-trip cut 8x:
// NCH 8->4 (256 blocks x 1024 threads; same 16 waves/CU, same 32 KB/phase
// staging) and bf16 partials (error 0.01*sqrt(256) ~ 0.2 << headroom).
// r12 lessons honored: ALL steady-state vmem is global_load_lds (no dest
// regs -> nothing for the allocator to sink; r8/r12's VGPR collapse), grid
// slice staged ONCE to LDS so the counted vmcnt stream holds weights only.
//
// Phase p (b=p&1):  issue W(p+1)->Wst[b^1]   (2 gload_lds/thread)
//                   rbf(cp)->As[b]           (Gs ds_reads, lgkm only)
//                   s_waitcnt vmcnt(2) lgkmcnt(0); s_barrier   // W(p) ready
//                   consume: af b128, 4x (8 ds_read_b32 + cvt) B-frags,
//                            4 MFMA (wave tile: mt=wv&3, nt=(wv>>2)*4+q)
//                   s_waitcnt lgkmcnt(0); s_barrier
// vmcnt counting: steady state exactly {W(p) x2, W(p+1) x2}; vmcnt(2)
// retires W(p) only. xv/prologue loads retire earlier (safe in any order:
// over-retiring only reduces overlap). Rotation s=(i+ch*8)&31 keeps addr
// bits 9-13 decorrelated across blocks (r10's confirmed +7us lever).
// Swizzles identical to r11 (Wst: source-unit XOR rr&7, read-side inverse;
// As: (row&3)<<3 on 32-short rows).  LDS 64+8+16 = 88 KB -> 1 block/CU.
// ---------------------------------------------------------------------------
__global__ __launch_bounds__(1024, 4)
void kan_main(const float* __restrict__ xg, const float* __restrict__ grd,
              const float* __restrict__ wts, unsigned short* __restrict__ dst,
              float* __restrict__ fdst, int atomic_mode)
{
    __shared__ __align__(16) float          Wst[2][OO * KP * 4]; // 32KB x2
    __shared__ __align__(16) unsigned short As [2][BB * KP];     //  4KB x2
    __shared__ __align__(16) float4         Gs [GC];             // 16KB

    const int i  = blockIdx.x;
    const int ch = blockIdx.y;
    const int g0 = ch * GC;                 // float4 index (1 per g)
    const int s  = (i + ch * 8) & (NPH - 1);

    const int t    = threadIdx.x;
    const int lane = t & 63;
    const int wv   = t >> 6;                // 0..15

    // rbf map: thread computes 2 g for one b-row
    const int brow = t >> 4;                // 0..63
    const int gq   = t & 15;
    const float4 xv = reinterpret_cast<const float4*>(xg)[brow * II + i];

    // ---- prologue: grid slice (16 KB) -> LDS, one inst/thread ----
    {
        const float4* gsrc = reinterpret_cast<const float4*>(grd) + g0 + t;
        char* ldst = (char*)(&Gs[0]) + wv * 1024;   // wave-uniform base
        __builtin_amdgcn_global_load_lds(gsrc, ldst, 16, 0, 0);
    }

    // weight staging: inst q covers rows 2j,2j+1 with j = q*16+wv;
    // lane: row_half = lane>>5, unit u = lane&31, source unit u^(rr&7).
    const float4* w4 = reinterpret_cast<const float4*>(wts)
                       + (size_t)i * OO * GG;
    const int srow_half = lane >> 5;
    const int su        = lane & 31;

    #pragma unroll
    for (int q = 0; q < 2; ++q) {                  // W(phase s) -> Wst[0]
        const int j  = q * 16 + wv;
        const int rr = 2 * j + srow_half;
        const int gg = g0 + s * KP + (su ^ (rr & 7));
        __builtin_amdgcn_global_load_lds(w4 + (size_t)rr * GG + gg,
            (char*)(&Wst[0][0]) + j * 1024, 16, 0, 0);
    }

    // Gs landed (oldest retired); W(s)'s 2 stay in flight
    asm volatile("s_waitcnt vmcnt(2)\n\ts_barrier" ::: "memory");

    f32x4 acc[4];
    #pragma unroll
    for (int q = 0; q < 4; ++q) acc[q] = {0.f, 0.f, 0.f, 0.f};

    const int mt  = wv & 3;          // wave's m-tile
    const int n4  = (wv >> 2) * 4;   // wave's first n-tile
    const int lg  = lane >> 4;
    const int r16 = lane & 15;
    const int bo  = r16 >> 2;        // o offset within an n-tile
    const int bx  = r16 & 3;         // x component

    for (int p = 0; p < NPH; ++p) {
        const int b  = p & 1;
        const int cp = (p + s) & (NPH - 1);
        const int np = (p + 1 + s) & (NPH - 1);

        // ---- issue W(np) -> Wst[b^1] (async, rides across barriers) ----
        if (p + 1 < NPH) {
            #pragma unroll
            for (int q = 0; q < 2; ++q) {
                const int j  = q * 16 + wv;
                const int rr = 2 * j + srow_half;
                const int gg = g0 + np * KP + (su ^ (rr & 7));
                __builtin_amdgcn_global_load_lds(w4 + (size_t)rr * GG + gg,
                    (char*)(&Wst[b ^ 1][0]) + j * 1024, 16, 0, 0);
            }
        }

        // ---- rbf(cp) -> As[b] (grid from LDS: lgkm only) ----
        {
            bf16x2 av;
            #pragma unroll
            for (int e = 0; e < 2; ++e) {
                const float4 g = Gs[cp * KP + gq * 2 + e];
                const float d0 = xv.x - g.x, d1 = xv.y - g.y,
                            d2 = xv.z - g.z, d3 = xv.w - g.w;
                av[e] = (short)f2bfu(__expf(-(d0*d0 + d1*d1 + d2*d2 + d3*d3)));
            }
            const int kb = gq * 2;
            *reinterpret_cast<bf16x2*>(
                &As[b][brow * KP + (kb ^ ((brow & 3) << 3))]) = av;
        }

        // ---- mid barrier: W(cp) landed (counted!), As[b] visible ----
        if (p + 1 < NPH)
            asm volatile("s_waitcnt vmcnt(2) lgkmcnt(0)\n\ts_barrier" ::: "memory");
        else
            asm volatile("s_waitcnt vmcnt(0) lgkmcnt(0)\n\ts_barrier" ::: "memory");

        // ---- consume: fragments + 4 MFMA ----
        const int rA = mt * 16 + r16;
        const bf16x8 af = *reinterpret_cast<const bf16x8*>(
            &As[b][rA * KP + ((lg * 8) ^ ((rA & 3) << 3))]);
        #pragma unroll
        for (int q = 0; q < 4; ++q) {
            const int o  = (n4 + q) * 4 + bo;
            const int sg = o & 7;
            const float* bp = &Wst[b][o * 128 + bx];
            bf16x8 bb;
            #pragma unroll
            for (int e = 0; e < 8; ++e)
                bb[e] = (short)f2bfu(bp[(lg * 8 + (e ^ sg)) * 4]);
            acc[q] = __builtin_amdgcn_mfma_f32_16x16x32_bf16(af, bb, acc[q],
                                                             0, 0, 0);
        }

        // ---- end barrier: LDS reads retired -> next phase may overwrite ----
        asm volatile("s_waitcnt lgkmcnt(0)\n\ts_barrier" ::: "memory");
    }

    // ---- epilogue: C/D col=lane&15 -> n, row=(lane>>4)*4+reg -> m ----
    const int mb = mt * 16 + (lane >> 4) * 4;
    if (!atomic_mode) {
        unsigned short* pd = dst + (size_t)(i * NCH + ch) * (BB * 256);
        #pragma unroll
        for (int q = 0; q < 4; ++q) {
            const int n = (n4 + q) * 16 + r16;
            #pragma unroll
            for (int r = 0; r < 4; ++r)
                pd[(mb + r) * 256 + n] = f2bfu(acc[q][r]);
        }
    } else {
        #pragma unroll
        for (int q = 0; q < 4; ++q) {
            const int n = (n4 + q) * 16 + r16;
            #pragma unroll
            for (int r = 0; r < 4; ++r)
                atomicAdd(&fdst[(mb + r) * 256 + n], acc[q][r]);
        }
    }
}

// ---------------------------------------------------------------------------
// Tail: sum 256 bf16 slices (8 MB) + SiLU/Cayley (Cl(2,0)) + bias
// ---------------------------------------------------------------------------
__global__ __launch_bounds__(256)
void kan_tail(const unsigned short* __restrict__ part,
              const float* __restrict__ xg,
              const float* __restrict__ sw,
              const float* __restrict__ sb,
              float* __restrict__ out)
{
    const int j = blockIdx.x * 256 + threadIdx.x;    // (b,o) in [0,4096)
    const int b = j >> 6, o = j & 63;

    const u16x4* p4 = reinterpret_cast<const u16x4*>(part);
    float o0 = 0.f, o1 = 0.f, o2 = 0.f, o3 = 0.f;
    #pragma unroll 8
    for (int sl = 0; sl < NSL; ++sl) {
        const u16x4 v = p4[(size_t)sl * 4096 + j];
        o0 += bfu2f(v[0]); o1 += bfu2f(v[1]);
        o2 += bfu2f(v[2]); o3 += bfu2f(v[3]);
    }

    const float4* xg4 = reinterpret_cast<const float4*>(xg);
    const float4* sw4 = reinterpret_cast<const float4*>(sw);
    const float4* sb4 = reinterpret_cast<const float4*>(sb);
    #pragma unroll 4
    for (int i = 0; i < II; ++i) {
        const float4 xvv = xg4[b * II + i];
        const float4 swv = sw4[i * OO + o];
        const float4 sbv = sb4[i * OO + o];
        const float s0 = xvv.x / (1.f + __expf(-xvv.x));
        const float s1 = xvv.y / (1.f + __expf(-xvv.y));
        const float s2 = xvv.z / (1.f + __expf(-xvv.z));
        const float s3 = xvv.w / (1.f + __expf(-xvv.w));
        o0 += swv.x * s0 + swv.y * s1 + swv.z * s2 - swv.w * s3 + sbv.x;
        o1 += swv.x * s1 + swv.y * s0 - swv.z * s3 + swv.w * s2 + sbv.y;
        o2 += swv.x * s2 + swv.y * s3 + swv.z * s0 - swv.w * s1 + sbv.z;
        o3 += swv.x * s3 + swv.y * s2 - swv.z * s1 + swv.w * s0 + sbv.w;
    }
    reinterpret_cast<float4*>(out)[j] = make_float4(o0, o1, o2, o3);
}

// ---------------------------------------------------------------------------
// Fallback-only final kernel (atomic path): main sums already in out
// ---------------------------------------------------------------------------
__global__ void kan_out(const float* __restrict__ xg,
                        const float* __restrict__ sw,
                        const float* __restrict__ sb,
                        float* __restrict__ out)
{
    const int t = blockIdx.x * 256 + threadIdx.x;    // (b,o)
    const int b = t >> 6, o = t & 63;

    const float4 v = reinterpret_cast<const float4*>(out)[t];
    float o0 = v.x, o1 = v.y, o2 = v.z, o3 = v.w;

    const float4* xg4 = reinterpret_cast<const float4*>(xg);
    const float4* sw4 = reinterpret_cast<const float4*>(sw);
    const float4* sb4 = reinterpret_cast<const float4*>(sb);
    #pragma unroll 4
    for (int i = 0; i < II; ++i) {
        const float4 xvv = xg4[b * II + i];
        const float4 swv = sw4[i * OO + o];
        const float4 sbv = sb4[i * OO + o];
        const float s0 = xvv.x / (1.f + __expf(-xvv.x));
        const float s1 = xvv.y / (1.f + __expf(-xvv.y));
        const float s2 = xvv.z / (1.f + __expf(-xvv.z));
        const float s3 = xvv.w / (1.f + __expf(-xvv.w));
        o0 += swv.x * s0 + swv.y * s1 + swv.z * s2 - swv.w * s3 + sbv.x;
        o1 += swv.x * s1 + swv.y * s0 - swv.z * s3 + swv.w * s2 + sbv.y;
        o2 += swv.x * s2 + swv.y * s3 + swv.z * s0 - swv.w * s1 + sbv.z;
        o3 += swv.x * s3 + swv.y * s2 - swv.z * s1 + swv.w * s0 + sbv.w;
    }
    reinterpret_cast<float4*>(out)[t] = make_float4(o0, o1, o2, o3);
}

// ---------------------------------------------------------------------------
extern "C" void kernel_launch(void* const* d_in, const int* in_sizes, int n_in,
                              void* d_out, int out_size, void* d_ws, size_t ws_size,
                              hipStream_t stream)
{
    const float* x   = (const float*)d_in[0];
    const float* grd = (const float*)d_in[1];
    const float* w   = (const float*)d_in[2];
    const float* sw  = (const float*)d_in[3];
    const float* sb  = (const float*)d_in[4];
    float* out = (float*)d_out;

    const size_t need = (size_t)NSL * 16384 * 2;   // 256 bf16 slices = 8 MB

    if (ws_size >= need) {
        unsigned short* ws = (unsigned short*)d_ws;
        kan_main<<<dim3(64, NCH), 1024, 0, stream>>>(x, grd, w, ws, nullptr, 0);
        kan_tail<<<16, 256, 0, stream>>>(ws, x, sw, sb, out);
    } else {
        hipMemsetAsync(d_out, 0, (size_t)out_size * sizeof(float), stream);
        kan_main<<<dim3(64, NCH), 1024, 0, stream>>>(x, grd, w, nullptr, out, 1);
        kan_out<<<16, 256, 0, stream>>>(x, sw, sb, out);
    }
}

// Round 14
// 72.456 us; speedup vs baseline: 3.8356x; 1.2774x over previous
//
#include <hip/hip_runtime.h>
#include <hip/hip_bf16.h>

// B=64, I=64, O=64, G=4096, X=4, RHO=1
#define BB 64
#define II 64
#define OO 64
#define GG 4096
#define KP 32            // g per phase
#define NCH 8            // split-K chunks -> grid 64 x 8 = 512 blocks
#define GC (GG / NCH)    // 512 g per block
#define NPH (GC / KP)    // 16 phases
#define NSL (II * NCH)   // 512 partial slices (bf16)

typedef short bf16x8 __attribute__((ext_vector_type(8)));
typedef short bf16x4 __attribute__((ext_vector_type(4)));
typedef float f32x4  __attribute__((ext_vector_type(4)));
typedef unsigned short u16x4 __attribute__((ext_vector_type(4)));

static __device__ __forceinline__ short f2bf(float f) {
    __hip_bfloat16 h = __float2bfloat16(f);
    return __builtin_bit_cast(short, h);
}
static __device__ __forceinline__ unsigned short f2bfu(float f) {
    __hip_bfloat16 h = __float2bfloat16(f);
    return __builtin_bit_cast(unsigned short, h);
}
static __device__ __forceinline__ float bfu2f(unsigned short u) {
    unsigned int v = (unsigned int)u << 16;
    return __builtin_bit_cast(float, v);
}

// ---------------------------------------------------------------------------
// r14 = r11 kan_main EXACTLY (76.2 us total; the proven 512-thr / NCH=8 /
// 80KB-LDS / 2-blocks-per-CU shape -- r13 proved 1 block/CU regresses 20%)
// with ONE change: partials stored as bf16 (numerics validated in r13).
// Structure: weights HBM->LDS raw f32 via global_load_lds (nothing for the
// allocator to sink -- r8/r12 lesson), double-buffered, counted s_waitcnt
// vmcnt(4) mid-loop (never 0), phase rotation s=(i+ch)&15 (r10's +7us).
// ---------------------------------------------------------------------------
__global__ __launch_bounds__(512, 4)
void kan_main(const float* __restrict__ xg, const float* __restrict__ grd,
              const float* __restrict__ wts, unsigned short* __restrict__ dst,
              float* __restrict__ fdst, int atomic_mode)
{
    __shared__ __align__(16) float          Wst[2][OO * KP * 4]; // 32KB x2
    __shared__ __align__(16) unsigned short As [2][BB * KP];     //  4KB x2
    __shared__ __align__(16) float4         Gs [GC];             //  8KB

    const int i  = blockIdx.x;
    const int ch = blockIdx.y;
    const int g0 = ch * GC;          // in float4 units (1 float4 per g)
    const int s  = (i + ch) & (NPH - 1);   // phase rotation offset

    const int t    = threadIdx.x;
    const int lane = t & 63;
    const int wv   = t >> 6;

    // rbf map: thread computes 4 g for one b-row
    const int brow = t >> 3;
    const int gq   = t & 7;
    const float4 xv = reinterpret_cast<const float4*>(xg)[brow * II + i];

    // ---- prologue: grid slice -> LDS (1 x 16B per thread) ----
    {
        const float4* gsrc = reinterpret_cast<const float4*>(grd) + g0 + t;
        char* ldst = (char*)(&Gs[0]) + wv * 1024;   // uniform per wave
        __builtin_amdgcn_global_load_lds(gsrc, ldst, 16, 0, 0);
    }

    // weight staging: inst q covers row-pair 2*(q*8+wv); lane supplies
    // row = +lane>>5, unit u = lane&31, fetched source unit u^(row&7).
    const float4* w4 = reinterpret_cast<const float4*>(wts)
                       + (size_t)i * OO * GG;
    const int srow_half = lane >> 5;
    const int su        = lane & 31;

    #pragma unroll
    for (int q = 0; q < 4; ++q) {                  // W(phase s) -> Wst[0]
        const int rr = 2 * (q * 8 + wv) + srow_half;
        const int gg = g0 + s * KP + (su ^ (rr & 7));
        __builtin_amdgcn_global_load_lds(w4 + (size_t)rr * GG + gg,
            (char*)(&Wst[0][0]) + (q * 8 + wv) * 1024, 16, 0, 0);
    }

    // grid (and xv) landed; W(s)'s 4 stay in flight
    asm volatile("s_waitcnt vmcnt(4)\n\ts_barrier" ::: "memory");

    f32x4 acc[4][2];
    #pragma unroll
    for (int mt = 0; mt < 4; ++mt)
        #pragma unroll
        for (int nt = 0; nt < 2; ++nt) acc[mt][nt] = {0.f, 0.f, 0.f, 0.f};

    const int lg    = lane >> 4;     // k-octet selector
    const int r16   = lane & 15;
    const int bo_lo = r16 >> 2;      // o offset within an nt quad
    const int bx    = r16 & 3;       // x component

    for (int p = 0; p < NPH; ++p) {
        const int b  = p & 1;
        const int cp = (p + s) & (NPH - 1);        // phase being computed
        const int np = (p + 1 + s) & (NPH - 1);    // phase being issued

        // ---- issue W(np) -> Wst[b^1] (async, rides across barriers) ----
        if (p + 1 < NPH) {
            #pragma unroll
            for (int q = 0; q < 4; ++q) {
                const int rr = 2 * (q * 8 + wv) + srow_half;
                const int gg = g0 + np * KP + (su ^ (rr & 7));
                __builtin_amdgcn_global_load_lds(w4 + (size_t)rr * GG + gg,
                    (char*)(&Wst[b ^ 1][0]) + (q * 8 + wv) * 1024, 16, 0, 0);
            }
        }

        // ---- rbf(cp) -> As[b] (grid from LDS: lgkm only) ----
        {
            bf16x4 av;
            #pragma unroll
            for (int e = 0; e < 4; ++e) {
                const float4 gv = Gs[cp * KP + gq * 4 + e];
                const float d0 = xv.x - gv.x, d1 = xv.y - gv.y,
                            d2 = xv.z - gv.z, d3 = xv.w - gv.w;
                av[e] = f2bf(__expf(-(d0*d0 + d1*d1 + d2*d2 + d3*d3)));
            }
            *reinterpret_cast<bf16x4*>(
                &As[b][brow * KP + ((gq * 4) ^ ((brow & 3) << 3))]) = av;
        }

        // ---- mid barrier: W(cp) landed (counted!), As[b] visible ----
        if (p + 1 < NPH)
            asm volatile("s_waitcnt vmcnt(4) lgkmcnt(0)\n\ts_barrier" ::: "memory");
        else
            asm volatile("s_waitcnt vmcnt(0) lgkmcnt(0)\n\ts_barrier" ::: "memory");

        // ---- consume: fragments + MFMA ----
        bf16x8 af[4];
        #pragma unroll
        for (int mt = 0; mt < 4; ++mt) {
            const int r = mt * 16 + r16;
            af[mt] = *reinterpret_cast<const bf16x8*>(
                &As[b][r * KP + ((lg * 8) ^ ((r & 3) << 3))]);
        }
        bf16x8 bb[2];
        #pragma unroll
        for (int nt = 0; nt < 2; ++nt) {
            const int o  = wv * 8 + nt * 4 + bo_lo;
            const int sg = o & 7;
            const float* bp = &Wst[b][o * 128 + bx];
            #pragma unroll
            for (int e = 0; e < 8; ++e)
                bb[nt][e] = f2bf(bp[(lg * 8 + (e ^ sg)) * 4]);
        }
        #pragma unroll
        for (int mt = 0; mt < 4; ++mt)
            #pragma unroll
            for (int nt = 0; nt < 2; ++nt)
                acc[mt][nt] = __builtin_amdgcn_mfma_f32_16x16x32_bf16(
                    af[mt], bb[nt], acc[mt][nt], 0, 0, 0);

        // ---- end barrier: this wave's LDS reads retired -> next phase may
        //      overwrite Wst[b^1]/As[b^1] ----
        asm volatile("s_waitcnt lgkmcnt(0)\n\ts_barrier" ::: "memory");
    }

    // ---- epilogue: C/D layout col=lane&15, row=(lane>>4)*4+reg ----
    // r14 change: store partials as bf16 (u16), halving the round-trip.
    if (!atomic_mode) {
        unsigned short* pd = dst + (size_t)(ch * 64 + i) * (BB * OO * 4);
        #pragma unroll
        for (int mt = 0; mt < 4; ++mt)
            #pragma unroll
            for (int nt = 0; nt < 2; ++nt) {
                const int n  = wv * 32 + nt * 16 + (lane & 15);
                const int mb = mt * 16 + ((lane >> 4) << 2);
                #pragma unroll
                for (int r = 0; r < 4; ++r)
                    pd[(mb + r) * 256 + n] = f2bfu(acc[mt][nt][r]);
            }
    } else {
        #pragma unroll
        for (int mt = 0; mt < 4; ++mt)
            #pragma unroll
            for (int nt = 0; nt < 2; ++nt) {
                const int n  = wv * 32 + nt * 16 + (lane & 15);
                const int mb = mt * 16 + ((lane >> 4) << 2);
                #pragma unroll
                for (int r = 0; r < 4; ++r)
                    atomicAdd(&fdst[(mb + r) * 256 + n], acc[mt][nt][r]);
            }
    }
}

// ---------------------------------------------------------------------------
// Fused tail (r11 shape, bf16 slices): 256 blocks; phase 1: 256 threads sum
// the 512 slices for the block's 16 (b,o) pairs (thread = pair x 32-slice
// group, fixed order -> deterministic); phase 2: 16 threads finish the
// 16-fold LDS reduce + 64-i SiLU/Cayley loop and write the final float4.
// ---------------------------------------------------------------------------
__global__ __launch_bounds__(256)
void kan_tail(const unsigned short* __restrict__ part,
              const float* __restrict__ xg,
              const float* __restrict__ sw,
              const float* __restrict__ sb,
              float* __restrict__ out)
{
    __shared__ float4 sums[16][16];          // [pairL][rgrp]

    const int t     = threadIdx.x;
    const int bid   = blockIdx.x;            // 0..255
    const int pairL = t & 15;
    const int rgrp  = t >> 4;
    const int pairG = bid * 16 + pairL;

    const u16x4* p4 = reinterpret_cast<const u16x4*>(part);
    float4 s = make_float4(0.f, 0.f, 0.f, 0.f);
    #pragma unroll 8
    for (int k = 0; k < 32; ++k) {
        const u16x4 v = p4[(size_t)(rgrp * 32 + k) * 4096 + pairG];
        s.x += bfu2f(v[0]); s.y += bfu2f(v[1]);
        s.z += bfu2f(v[2]); s.w += bfu2f(v[3]);
    }
    sums[pairL][rgrp] = s;
    __syncthreads();

    if (t < 16) {
        const int pg = bid * 16 + t;
        const int b = pg >> 6, o = pg & 63;

        float o0 = 0.f, o1 = 0.f, o2 = 0.f, o3 = 0.f;
        #pragma unroll
        for (int r = 0; r < 16; ++r) {
            const float4 v = sums[t][r];
            o0 += v.x; o1 += v.y; o2 += v.z; o3 += v.w;
        }

        const float4* xg4 = reinterpret_cast<const float4*>(xg);
        const float4* sw4 = reinterpret_cast<const float4*>(sw);
        const float4* sb4 = reinterpret_cast<const float4*>(sb);
        #pragma unroll 4
        for (int i = 0; i < II; ++i) {
            const float4 xvv = xg4[b * II + i];
            const float4 swv = sw4[i * OO + o];
            const float4 sbv = sb4[i * OO + o];
            const float s0 = xvv.x / (1.f + __expf(-xvv.x));
            const float s1 = xvv.y / (1.f + __expf(-xvv.y));
            const float s2 = xvv.z / (1.f + __expf(-xvv.z));
            const float s3 = xvv.w / (1.f + __expf(-xvv.w));
            o0 += swv.x * s0 + swv.y * s1 + swv.z * s2 - swv.w * s3 + sbv.x;
            o1 += swv.x * s1 + swv.y * s0 - swv.z * s3 + swv.w * s2 + sbv.y;
            o2 += swv.x * s2 + swv.y * s3 + swv.z * s0 - swv.w * s1 + sbv.z;
            o3 += swv.x * s3 + swv.y * s2 - swv.z * s1 + swv.w * s0 + sbv.w;
        }
        reinterpret_cast<float4*>(out)[pg] = make_float4(o0, o1, o2, o3);
    }
}

// ---------------------------------------------------------------------------
// Fallback-only final kernel (atomic path): main sums already in out
// ---------------------------------------------------------------------------
__global__ void kan_out(const float* __restrict__ xg,
                        const float* __restrict__ sw,
                        const float* __restrict__ sb,
                        float* __restrict__ out)
{
    const int t = blockIdx.x * 256 + threadIdx.x;    // (b,o)
    const int b = t >> 6, o = t & 63;

    const float4 v = reinterpret_cast<const float4*>(out)[t];
    float o0 = v.x, o1 = v.y, o2 = v.z, o3 = v.w;

    const float4* xg4 = reinterpret_cast<const float4*>(xg);
    const float4* sw4 = reinterpret_cast<const float4*>(sw);
    const float4* sb4 = reinterpret_cast<const float4*>(sb);
    #pragma unroll 4
    for (int i = 0; i < II; ++i) {
        const float4 xvv = xg4[b * II + i];
        const float4 swv = sw4[i * OO + o];
        const float4 sbv = sb4[i * OO + o];
        const float s0 = xvv.x / (1.f + __expf(-xvv.x));
        const float s1 = xvv.y / (1.f + __expf(-xvv.y));
        const float s2 = xvv.z / (1.f + __expf(-xvv.z));
        const float s3 = xvv.w / (1.f + __expf(-xvv.w));
        o0 += swv.x * s0 + swv.y * s1 + swv.z * s2 - swv.w * s3 + sbv.x;
        o1 += swv.x * s1 + swv.y * s0 - swv.z * s3 + swv.w * s2 + sbv.y;
        o2 += swv.x * s2 + swv.y * s3 + swv.z * s0 - swv.w * s1 + sbv.z;
        o3 += swv.x * s3 + swv.y * s2 - swv.z * s1 + swv.w * s0 + sbv.w;
    }
    reinterpret_cast<float4*>(out)[t] = make_float4(o0, o1, o2, o3);
}

// ---------------------------------------------------------------------------
extern "C" void kernel_launch(void* const* d_in, const int* in_sizes, int n_in,
                              void* d_out, int out_size, void* d_ws, size_t ws_size,
                              hipStream_t stream)
{
    const float* x   = (const float*)d_in[0];
    const float* grd = (const float*)d_in[1];
    const float* w   = (const float*)d_in[2];
    const float* sw  = (const float*)d_in[3];
    const float* sb  = (const float*)d_in[4];
    float* out = (float*)d_out;

    const size_t need = (size_t)NSL * 16384 * 2;   // 512 bf16 slices = 16 MB

    if (ws_size >= need) {
        unsigned short* ws = (unsigned short*)d_ws;
        kan_main<<<dim3(64, NCH), 512, 0, stream>>>(x, grd, w, ws, nullptr, 0);
        kan_tail<<<256, 256, 0, stream>>>(ws, x, sw, sb, out);
    } else {
        hipMemsetAsync(d_out, 0, (size_t)out_size * sizeof(float), stream);
        kan_main<<<dim3(64, NCH), 512, 0, stream>>>(x, grd, w, nullptr, out, 1);
        kan_out<<<16, 256, 0, stream>>>(x, sw, sb, out);
    }
}

// Round 15
// 70.592 us; speedup vs baseline: 3.9368x; 1.0264x over previous
//
#include <hip/hip_runtime.h>
#include <hip/hip_bf16.h>

// B=64, I=64, O=64, G=4096, X=4, RHO=1
#define BB 64
#define II 64
#define OO 64
#define GG 4096
#define KP 64            // g per phase
#define NPH 16           // phases (1024 g per block / 64)
#define NSL 512          // partial slices (bf16), 8 MB

typedef short bf16x8 __attribute__((ext_vector_type(8)));
typedef float f32x4  __attribute__((ext_vector_type(4)));
typedef unsigned short u16x4 __attribute__((ext_vector_type(4)));

static __device__ __forceinline__ short f2bf(float f) {
    __hip_bfloat16 h = __float2bfloat16(f);
    return __builtin_bit_cast(short, h);
}
static __device__ __forceinline__ unsigned short f2bfu(float f) {
    __hip_bfloat16 h = __float2bfloat16(f);
    return __builtin_bit_cast(unsigned short, h);
}
static __device__ __forceinline__ float bfu2f(unsigned short u) {
    unsigned int v = (unsigned int)u << 16;
    return __builtin_bit_cast(float, v);
}

// ---------------------------------------------------------------------------
// r15: SEQUENTIAL-STREAM tiling. Block (i, oc half, gch quarter) owns 32
// o-rows x 1024 g; 16 phases of KP=64. Each wave stages 4 rows/phase as ONE
// 1-KB contiguous gload_lds per row; consecutive phases read consecutive
// 1-KB chunks of the same row -> 16-KB sequential per-row streams (vs
// r14's 512-B extents at 64-KB stride). Occupancy = r14 (2 blk/CU, 16
// waves/CU). Counted vmcnt(4) mid-loop; grid staged via gload_lds into a
// rolling 1-KB Gs INSIDE the counted stream. As is SINGLE-buffered: rbf(np)
// computed to regs during phase p, written to As after the end-barrier
// (all As(cp) reads drained by lgkmcnt(0)+barrier -> race-free).
//
// Wst store swizzle (per 1-KB row, 64 16-B units): slot u holds source unit
// u ^ qs, qs = ((row&3)<<1)|((u>>3)&1)  (involution: qs doesn't flip bit 3).
// Consume b32 read of (row,g,x): slot = g ^ qs(row,g); bank = 4*((g^qs)&7)+x
// spans 32 banks over the wave -> 2-way (free; r14 was 4-way).
// As swizzle: unit ^= (row&7), rows of 64 bf16 (8 units) -- m201 pattern.
//
// Per-phase per-wave: 4 W-loads + 1 G-load (all waves issue the same G ->
// L2 dedup), vmcnt(4) retires {W(cp) x4, G(np)}; 8 ds_read_b128 af +
// 16 b32 bb + 8 MFMA. LDS 64+8+1 = 73 KB.
// ---------------------------------------------------------------------------
__global__ __launch_bounds__(512, 4)
void kan_main(const float* __restrict__ xg, const float* __restrict__ grd,
              const float* __restrict__ wts, unsigned short* __restrict__ dst,
              float* __restrict__ fdst, int atomic_mode)
{
    __shared__ __align__(16) float          Wst[2][32 * 256]; // 32KB x2
    __shared__ __align__(16) unsigned short As [BB * KP];     //  8KB
    __shared__ __align__(16) float4         Gs [KP];          //  1KB

    const int i   = blockIdx.x;          // 0..63
    const int oc  = blockIdx.y;          // 0..1   o-half
    const int gch = blockIdx.z;          // 0..3   g-quarter
    const int s   = (i + 4 * gch + 8 * oc) & (NPH - 1);

    const int t    = threadIdx.x;
    const int lane = t & 63;
    const int wv   = t >> 6;             // 0..7

    // rbf map: thread computes 8 g for one b-row
    const int brow = t >> 3;
    const int oct  = t & 7;
    const float4 xv = reinterpret_cast<const float4*>(xg)[brow * II + i];

    // weights: 4 rows per wave (rr = q*8+wv), contiguous 1 KB per phase
    const float4* w4 = reinterpret_cast<const float4*>(wts)
        + ((size_t)i * OO + oc * 32) * GG + (size_t)gch * 1024;
    const float4* g4 = reinterpret_cast<const float4*>(grd) + gch * 1024;
    const int qs_hi = (lane >> 3) & 1;   // store-swizzle bit from slot

    // ---- prologue ----
    __builtin_amdgcn_global_load_lds(g4 + s * KP + lane, (char*)(&Gs[0]),
                                     16, 0, 0);
    #pragma unroll
    for (int q = 0; q < 4; ++q) {
        const int rr = q * 8 + wv;
        const int qs = ((rr & 3) << 1) | qs_hi;
        __builtin_amdgcn_global_load_lds(
            w4 + (size_t)rr * GG + s * KP + (lane ^ qs),
            (char*)(&Wst[0][0]) + rr * 1024, 16, 0, 0);
    }
    asm volatile("s_waitcnt vmcnt(4)" ::: "memory");   // xv + G(s) landed

    {   // rbf(s) -> As (no readers yet)
        bf16x8 pa;
        #pragma unroll
        for (int e = 0; e < 8; ++e) {
            const float4 g = Gs[oct * 8 + e];
            const float d0 = xv.x - g.x, d1 = xv.y - g.y,
                        d2 = xv.z - g.z, d3 = xv.w - g.w;
            pa[e] = f2bf(__expf(-(d0*d0 + d1*d1 + d2*d2 + d3*d3)));
        }
        *reinterpret_cast<bf16x8*>(
            &As[brow * KP + ((oct * 8) ^ ((brow & 7) << 3))]) = pa;
    }
    asm volatile("s_waitcnt lgkmcnt(0)\n\ts_barrier" ::: "memory");
    // Gs free -> issue G(s+1)
    __builtin_amdgcn_global_load_lds(g4 + ((s + 1) & (NPH - 1)) * KP + lane,
                                     (char*)(&Gs[0]), 16, 0, 0);

    f32x4 acc[4];
    #pragma unroll
    for (int mt = 0; mt < 4; ++mt) acc[mt] = {0.f, 0.f, 0.f, 0.f};

    const int lg   = lane >> 4;
    const int r16  = lane & 15;
    const int orow = wv * 4 + (r16 >> 2);  // wave's o-rows (nt = wv)
    const int bx   = r16 & 3;

    for (int p = 0; p < NPH; ++p) {
        const int b  = p & 1;
        const int cp = (p + s) & (NPH - 1);
        const int np = (p + 1 + s) & (NPH - 1);

        // 1. issue W(np) -> Wst[b^1]
        if (p + 1 < NPH) {
            #pragma unroll
            for (int q = 0; q < 4; ++q) {
                const int rr = q * 8 + wv;
                const int qs = ((rr & 3) << 1) | qs_hi;
                __builtin_amdgcn_global_load_lds(
                    w4 + (size_t)rr * GG + np * KP + (lane ^ qs),
                    (char*)(&Wst[b ^ 1][0]) + rr * 1024, 16, 0, 0);
            }
        }

        // 2. counted wait: retires {W(cp) x4, G(np)}; W(np) stays in flight
        if (p + 1 < NPH)
            asm volatile("s_waitcnt vmcnt(4)" ::: "memory");
        else
            asm volatile("s_waitcnt vmcnt(0)" ::: "memory");

        // 3. rbf(np) -> regs (Gs holds chunk np)
        bf16x8 pa;
        if (p + 1 < NPH) {
            #pragma unroll
            for (int e = 0; e < 8; ++e) {
                const float4 g = Gs[oct * 8 + e];
                const float d0 = xv.x - g.x, d1 = xv.y - g.y,
                            d2 = xv.z - g.z, d3 = xv.w - g.w;
                pa[e] = f2bf(__expf(-(d0*d0 + d1*d1 + d2*d2 + d3*d3)));
            }
        }

        // 5. mid barrier: Wst[b] (all waves) + As(cp) writes visible
        asm volatile("s_waitcnt lgkmcnt(0)\n\ts_barrier" ::: "memory");

        // 6. consume: per kk build bb once, af x4 mt, 8 MFMA
        #pragma unroll
        for (int kk = 0; kk < 2; ++kk) {
            bf16x8 bb;
            #pragma unroll
            for (int e = 0; e < 8; ++e) {
                const int g  = kk * 32 + lg * 8 + e;
                const int qp = ((orow & 3) << 1) | (lg & 1);
                bb[e] = f2bf(Wst[b][orow * 256 + ((g ^ qp) << 2) + bx]);
            }
            #pragma unroll
            for (int mt = 0; mt < 4; ++mt) {
                const int rA = mt * 16 + r16;
                const bf16x8 af = *reinterpret_cast<const bf16x8*>(
                    &As[rA * KP + ((kk * 32 + lg * 8) ^ ((rA & 7) << 3))]);
                acc[mt] = __builtin_amdgcn_mfma_f32_16x16x32_bf16(
                    af, bb, acc[mt], 0, 0, 0);
            }
        }

        // 7. end barrier: all As/Wst/Gs reads of this phase retired
        asm volatile("s_waitcnt lgkmcnt(0)\n\ts_barrier" ::: "memory");

        // 8. write As <- rbf(np) (safe: all As(cp) reads drained)
        if (p + 1 < NPH) {
            *reinterpret_cast<bf16x8*>(
                &As[brow * KP + ((oct * 8) ^ ((brow & 7) << 3))]) = pa;
        }
        // 9. issue G(np2) -> Gs (safe: all Gs reads drained)
        if (p + 2 < NPH) {
            __builtin_amdgcn_global_load_lds(
                g4 + ((p + 2 + s) & (NPH - 1)) * KP + lane,
                (char*)(&Gs[0]), 16, 0, 0);
        }
    }

    // ---- epilogue: C/D col=lane&15 -> n-local, row=(lane>>4)*4+r -> m ----
    const int nloc = wv * 16 + r16;          // 0..127
    const int mb   = ((lane >> 4) << 2);
    if (!atomic_mode) {
        unsigned short* pd = dst
            + (size_t)((i * 2 + oc) * 4 + gch) * (BB * 128);
        #pragma unroll
        for (int mt = 0; mt < 4; ++mt)
            #pragma unroll
            for (int r = 0; r < 4; ++r)
                pd[(mt * 16 + mb + r) * 128 + nloc] = f2bfu(acc[mt][r]);
    } else {
        #pragma unroll
        for (int mt = 0; mt < 4; ++mt)
            #pragma unroll
            for (int r = 0; r < 4; ++r)
                atomicAdd(&fdst[(mt * 16 + mb + r) * 256 + oc * 128 + nloc],
                          acc[mt][r]);
    }
}

// ---------------------------------------------------------------------------
// Fused tail: 256 blocks. Pair (b,o): sum 256 slices (i x gch for oc=o>>5),
// 16 threads/pair x 16 slices each -> LDS reduce -> 16 finisher threads do
// the 64-i SiLU/Cayley (Cl(2,0), static signs) + bias and write float4.
// Slice sl = (i*2+oc)*4+gch, layout [64 b][128 n] bf16; n = (o&31)*4+x.
// ---------------------------------------------------------------------------
__global__ __launch_bounds__(256)
void kan_tail(const unsigned short* __restrict__ part,
              const float* __restrict__ xg,
              const float* __restrict__ sw,
              const float* __restrict__ sb,
              float* __restrict__ out)
{
    __shared__ float4 sums[16][16];

    const int t     = threadIdx.x;
    const int bid   = blockIdx.x;            // 0..255
    const int pairL = t & 15;
    const int rgrp  = t >> 4;
    const int pairG = bid * 16 + pairL;
    const int b     = pairG >> 6, o = pairG & 63;
    const int oc    = o >> 5;

    float4 s4 = make_float4(0.f, 0.f, 0.f, 0.f);
    #pragma unroll 4
    for (int m = 0; m < 16; ++m) {
        const int idx = rgrp * 16 + m;       // (i, gch) pair
        const int ii  = idx >> 2, gg = idx & 3;
        const size_t sl = (size_t)((ii * 2 + oc) * 4 + gg);
        const u16x4 v = *reinterpret_cast<const u16x4*>(
            part + sl * (BB * 128) + b * 128 + (o & 31) * 4);
        s4.x += bfu2f(v[0]); s4.y += bfu2f(v[1]);
        s4.z += bfu2f(v[2]); s4.w += bfu2f(v[3]);
    }
    sums[pairL][rgrp] = s4;
    __syncthreads();

    if (t < 16) {
        const int pg = bid * 16 + t;
        const int bb = pg >> 6, oo = pg & 63;

        float o0 = 0.f, o1 = 0.f, o2 = 0.f, o3 = 0.f;
        #pragma unroll
        for (int r = 0; r < 16; ++r) {
            const float4 v = sums[t][r];
            o0 += v.x; o1 += v.y; o2 += v.z; o3 += v.w;
        }

        const float4* xg4 = reinterpret_cast<const float4*>(xg);
        const float4* sw4 = reinterpret_cast<const float4*>(sw);
        const float4* sb4 = reinterpret_cast<const float4*>(sb);
        #pragma unroll 4
        for (int i = 0; i < II; ++i) {
            const float4 xvv = xg4[bb * II + i];
            const float4 swv = sw4[i * OO + oo];
            const float4 sbv = sb4[i * OO + oo];
            const float s0 = xvv.x / (1.f + __expf(-xvv.x));
            const float s1 = xvv.y / (1.f + __expf(-xvv.y));
            const float s2 = xvv.z / (1.f + __expf(-xvv.z));
            const float s3 = xvv.w / (1.f + __expf(-xvv.w));
            o0 += swv.x * s0 + swv.y * s1 + swv.z * s2 - swv.w * s3 + sbv.x;
            o1 += swv.x * s1 + swv.y * s0 - swv.z * s3 + swv.w * s2 + sbv.y;
            o2 += swv.x * s2 + swv.y * s3 + swv.z * s0 - swv.w * s1 + sbv.z;
            o3 += swv.x * s3 + swv.y * s2 - swv.z * s1 + swv.w * s0 + sbv.w;
        }
        reinterpret_cast<float4*>(out)[pg] = make_float4(o0, o1, o2, o3);
    }
}

// ---------------------------------------------------------------------------
// Fallback-only final kernel (atomic path): main sums already in out
// ---------------------------------------------------------------------------
__global__ void kan_out(const float* __restrict__ xg,
                        const float* __restrict__ sw,
                        const float* __restrict__ sb,
                        float* __restrict__ out)
{
    const int t = blockIdx.x * 256 + threadIdx.x;    // (b,o)
    const int b = t >> 6, o = t & 63;

    const float4 v = reinterpret_cast<const float4*>(out)[t];
    float o0 = v.x, o1 = v.y, o2 = v.z, o3 = v.w;

    const float4* xg4 = reinterpret_cast<const float4*>(xg);
    const float4* sw4 = reinterpret_cast<const float4*>(sw);
    const float4* sb4 = reinterpret_cast<const float4*>(sb);
    #pragma unroll 4
    for (int i = 0; i < II; ++i) {
        const float4 xvv = xg4[b * II + i];
        const float4 swv = sw4[i * OO + o];
        const float4 sbv = sb4[i * OO + o];
        const float s0 = xvv.x / (1.f + __expf(-xvv.x));
        const float s1 = xvv.y / (1.f + __expf(-xvv.y));
        const float s2 = xvv.z / (1.f + __expf(-xvv.z));
        const float s3 = xvv.w / (1.f + __expf(-xvv.w));
        o0 += swv.x * s0 + swv.y * s1 + swv.z * s2 - swv.w * s3 + sbv.x;
        o1 += swv.x * s1 + swv.y * s0 - swv.z * s3 + swv.w * s2 + sbv.y;
        o2 += swv.x * s2 + swv.y * s3 + swv.z * s0 - swv.w * s1 + sbv.z;
        o3 += swv.x * s3 + swv.y * s2 - swv.z * s1 + swv.w * s0 + sbv.w;
    }
    reinterpret_cast<float4*>(out)[t] = make_float4(o0, o1, o2, o3);
}

// ---------------------------------------------------------------------------
extern "C" void kernel_launch(void* const* d_in, const int* in_sizes, int n_in,
                              void* d_out, int out_size, void* d_ws, size_t ws_size,
                              hipStream_t stream)
{
    const float* x   = (const float*)d_in[0];
    const float* grd = (const float*)d_in[1];
    const float* w   = (const float*)d_in[2];
    const float* sw  = (const float*)d_in[3];
    const float* sb  = (const float*)d_in[4];
    float* out = (float*)d_out;

    const size_t need = (size_t)NSL * (BB * 128) * 2;   // 8 MB

    if (ws_size >= need) {
        unsigned short* ws = (unsigned short*)d_ws;
        kan_main<<<dim3(64, 2, 4), 512, 0, stream>>>(x, grd, w, ws, nullptr, 0);
        kan_tail<<<256, 256, 0, stream>>>(ws, x, sw, sb, out);
    } else {
        hipMemsetAsync(d_out, 0, (size_t)out_size * sizeof(float), stream);
        kan_main<<<dim3(64, 2, 4), 512, 0, stream>>>(x, grd, w, nullptr, out, 1);
        kan_out<<<16, 256, 0, stream>>>(x, sw, sb, out);
    }
}